// Round 4
// baseline (379.522 us; speedup 1.0000x reference)
//
#include <hip/hip_runtime.h>
#include <cstdint>
#include <cstddef>

#define EPSV 1e-5f
#define TEMP_MINV 0.01f

typedef __attribute__((ext_vector_type(8))) short bf16x8;
typedef __attribute__((ext_vector_type(4))) float f32x4;

__device__ inline short f2bf(float f) {
    unsigned u = __float_as_uint(f);
    unsigned r = (u + 0x7fffu + ((u >> 16) & 1u)) >> 16;
    return (short)r;
}

__device__ inline void gload16(const void* g, void* l) {
    __builtin_amdgcn_global_load_lds(
        (const __attribute__((address_space(1))) void*)g,
        (__attribute__((address_space(3))) void*)l, 16, 0, 0);
}

// residual entering level l is exactly 0 iff any earlier scale == 1.0f
// (r - (r*1)/1 == 0 exactly in fp). Cheap: L scalar loads, inline everywhere.
__device__ inline int lvl_flag(const float* __restrict__ scales, int l) {
    int f = 0;
    for (int j = 0; j < l; ++j) f |= (scales[j] == 1.0f) ? 1 : 0;
    return f;
}

// ---- pack 32 rows of fp32 [R][512] -> bf16 packed [64][R][8] (one 256-thread block) ----
__device__ inline void pack_block(const float* __restrict__ in, short* __restrict__ outp,
                                  int R, int rb, short* lds) {
    const int t = threadIdx.x;
    const float4* in4 = (const float4*)(in + (size_t)rb * 512);
    #pragma unroll
    for (int it = 0; it < 16; ++it) {
        const int flat = it * 1024 + t * 4;
        float4 v = in4[flat >> 2];
        const int row = flat >> 9, col = flat & 511;
        short4 o; o.x = f2bf(v.x); o.y = f2bf(v.y); o.z = f2bf(v.z); o.w = f2bf(v.w);
        *(short4*)&lds[row * 520 + col] = o;
    }
    __syncthreads();
    #pragma unroll
    for (int it = 0; it < 8; ++it) {
        const int c = it * 256 + t;
        const int kb = c >> 5, r = c & 31;
        int4 v = *(const int4*)&lds[r * 520 + kb * 8];
        *(int4*)(outp + ((size_t)kb * R + rb + r) * 8) = v;
    }
}

// same, but applies the residual recurrence through level l then scales by scales[l]
// (fallback path only)
__device__ inline void pack_block_rec(const float* __restrict__ in, short* __restrict__ outp,
                                      int R, int rb, short* lds,
                                      const float* __restrict__ scales, int l) {
    const int t = threadIdx.x;
    const float4* in4 = (const float4*)(in + (size_t)rb * 512);
    #pragma unroll
    for (int it = 0; it < 16; ++it) {
        const int flat = it * 1024 + t * 4;
        float4 v = in4[flat >> 2];
        float e[4] = {v.x, v.y, v.z, v.w};
        for (int j = 0; j < l; ++j) {
            const float sc = scales[j];
            #pragma unroll
            for (int q = 0; q < 4; ++q) { float rv = e[q] * sc; e[q] = e[q] - rv / sc; }
        }
        const float sl = scales[l];
        const int row = flat >> 9, col = flat & 511;
        short4 o;
        o.x = f2bf(e[0] * sl); o.y = f2bf(e[1] * sl);
        o.z = f2bf(e[2] * sl); o.w = f2bf(e[3] * sl);
        *(short4*)&lds[row * 520 + col] = o;
    }
    __syncthreads();
    #pragma unroll
    for (int it = 0; it < 8; ++it) {
        const int c = it * 256 + t;
        const int kb = c >> 5, r = c & 31;
        int4 v = *(const int4*)&lds[r * 520 + kb * 8];
        *(int4*)(outp + ((size_t)kb * R + rb + r) * 8) = v;
    }
}

// ---------------- input prep (one launch): pack features | pack W | pack cb L0 |
//                  cb row norms (all levels) | gated cb packs for levels >=1 ----------------
__global__ __launch_bounds__(256) void prep_inputs(
    const float* __restrict__ features, const float* __restrict__ W,
    const float* __restrict__ cb, const float* __restrict__ scales,
    short* __restrict__ P1, short* __restrict__ Wp, short* __restrict__ cbp0,
    short* __restrict__ cbpL, float* __restrict__ cn,
    int M, int D, int K, int L, int LK, int merged) {
    __shared__ __align__(16) short lds[32 * 520];
    int gid = blockIdx.x;
    const int nF = M / 32, nW = D / 32, nC = K / 32;
    if (gid < nF) { pack_block(features, P1, M, gid * 32, lds); return; }
    gid -= nF;
    if (gid < nW) { pack_block(W, Wp, D, gid * 32, lds); return; }
    gid -= nW;
    if (gid < nC) { pack_block(cb, cbp0, K, gid * 32, lds); return; }
    gid -= nC;
    const int nNorm = (LK + 15) / 16;
    if (gid < nNorm) {
        // 16 rows/block: wave wv handles 4 rows sequentially
        const int wv = threadIdx.x >> 6, lane = threadIdx.x & 63;
        #pragma unroll
        for (int rr = 0; rr < 4; ++rr) {
            const int row = gid * 16 + wv * 4 + rr;
            if (row >= LK) continue;
            const float* p = cb + (size_t)row * 512;
            float s = 0.f;
            for (int j = lane; j < 512; j += 64) { float v = p[j]; s += v * v; }
            #pragma unroll
            for (int off = 32; off; off >>= 1) s += __shfl_down(s, off);
            if (lane == 0) cn[row] = s;
        }
        return;
    }
    gid -= nNorm;
    // gated cb packs for levels 1..L-1 (merged mode only; no-op when level flagged)
    const int lvl = 1 + gid / nC;
    if (!merged || lvl_flag(scales, lvl)) return;
    const int sub = gid % nC;
    pack_block(cb + (size_t)lvl * K * D, cbpL + (size_t)(lvl - 1) * K * D, K, sub * 32, lds);
}

// ---------------- GEMM1 (MFMA) + HALF of flagged-level broadcast (rows 0..63/tile) ----------
__global__ __launch_bounds__(256) void gemm1_bcast(
    const short* __restrict__ Ap, const short* __restrict__ Bp,
    const float* __restrict__ bias, float* __restrict__ Y,
    const float* __restrict__ cn, const float* __restrict__ temp_p,
    const float* __restrict__ scales, float* __restrict__ out,
    int M, int N, int Kd, int K, int LK) {
    __shared__ __align__(16) short As[8 * 128 * 8];
    __shared__ __align__(16) short Bs[8 * 128 * 8];
    const int by = blockIdx.y, nyG = N >> 7;
    if (by >= nyG) {
        const int bcg = by - nyG;
        const int G = K >> 7;
        const int lvl = 1 + bcg / G;
        if (!lvl_flag(scales, lvl)) return;       // unflagged -> dist_all / fallback
        const int cg0 = lvl * K + (bcg % G) * 128;
        const float inv_t = 1.0f / fmaxf(temp_p[0], TEMP_MINV);
        const int r0 = blockIdx.x * 128;
        const int tc = (threadIdx.x & 31) << 2, tr = threadIdx.x >> 5;
        float4 cv = *(const float4*)(cn + cg0 + tc);
        float4 v = make_float4(-cv.x * inv_t, -cv.y * inv_t, -cv.z * inv_t, -cv.w * inv_t);
        #pragma unroll
        for (int i = 0; i < 8; ++i) {             // rows 0..63 of tile (dist_all does 64..127)
            const int r = r0 + i * 8 + tr;
            *(float4*)(out + (size_t)r * LK + cg0 + tc) = v;
        }
        return;
    }
    const int r0 = blockIdx.x * 128, c0 = by * 128;
    const int lane = threadIdx.x & 63, w = threadIdx.x >> 6;
    const int wm = (w & 1) << 6, wn = (w >> 1) << 6;
    const int fr = lane & 15, fo = lane >> 4;
    f32x4 acc[4][4];
    #pragma unroll
    for (int a = 0; a < 4; ++a)
        #pragma unroll
        for (int b = 0; b < 4; ++b) acc[a][b] = (f32x4){0.f, 0.f, 0.f, 0.f};
    for (int k0 = 0; k0 < Kd; k0 += 64) {
        const int kb0 = k0 >> 3;
        __syncthreads();
        #pragma unroll
        for (int sidx = 0; sidx < 2; ++sidx) {
            const int kblk = (w << 1) + sidx;
            const short* ga = Ap + ((size_t)(kb0 + kblk) * M + r0) * 8;
            const short* gb = Bp + ((size_t)(kb0 + kblk) * N + c0) * 8;
            short* la = &As[kblk * 128 * 8];
            short* lb = &Bs[kblk * 128 * 8];
            #pragma unroll
            for (int h = 0; h < 2; ++h) {
                gload16(ga + ((h << 6) + lane) * 8, la + (h << 6) * 8);
                gload16(gb + ((h << 6) + lane) * 8, lb + (h << 6) * 8);
            }
        }
        __syncthreads();
        #pragma unroll
        for (int s = 0; s < 2; ++s) {
            const int kb = (s << 2) + fo;
            bf16x8 af[4], bfv[4];
            #pragma unroll
            for (int mt = 0; mt < 4; ++mt)
                af[mt] = *(const bf16x8*)&As[(kb * 128 + wm + mt * 16 + fr) * 8];
            #pragma unroll
            for (int nt = 0; nt < 4; ++nt)
                bfv[nt] = *(const bf16x8*)&Bs[(kb * 128 + wn + nt * 16 + fr) * 8];
            #pragma unroll
            for (int mt = 0; mt < 4; ++mt)
                #pragma unroll
                for (int nt = 0; nt < 4; ++nt)
                    acc[mt][nt] = __builtin_amdgcn_mfma_f32_16x16x32_bf16(af[mt], bfv[nt], acc[mt][nt], 0, 0, 0);
        }
    }
    #pragma unroll
    for (int mt = 0; mt < 4; ++mt) {
        #pragma unroll
        for (int reg = 0; reg < 4; ++reg) {
            const int r = r0 + wm + mt * 16 + (fo << 2) + reg;
            float* orow = Y + (size_t)r * N;
            #pragma unroll
            for (int nt = 0; nt < 4; ++nt) {
                const int c = c0 + wn + nt * 16 + fr;
                orow[c] = acc[mt][nt][reg] + bias[c];
            }
        }
    }
}

// ---------------- fused epilogue: LN(affine)+ReLU ; per-level residual pack + norms
//                  (ALL active levels, in registers) ; qsum ; LN(qsum) -> out_ln ----------------
__global__ __launch_bounds__(256) void fused_epi(
    const float* __restrict__ Yin, float* __restrict__ Xout,
    short* __restrict__ P1, float* __restrict__ rsn, float* __restrict__ outln,
    const float* __restrict__ g, const float* __restrict__ b,
    const float* __restrict__ scales,
    short* __restrict__ P1L, float* __restrict__ rsnL,
    int M, int L, int merged) {
    __shared__ __align__(16) short plds[4 * 520];
    const int lane = threadIdx.x & 63, wv = threadIdx.x >> 6;
    const int rb = blockIdx.x * 4;
    const int r = rb + wv;
    const float* p = Yin + (size_t)r * 512 + lane * 8;
    float4 v0 = *(const float4*)p;
    float4 v1 = *(const float4*)(p + 4);
    float e[8] = {v0.x, v0.y, v0.z, v0.w, v1.x, v1.y, v1.z, v1.w};
    float s = 0.f;
    #pragma unroll
    for (int j = 0; j < 8; ++j) s += e[j];
    #pragma unroll
    for (int off = 1; off < 64; off <<= 1) s += __shfl_xor(s, off);
    const float mu = s * (1.0f / 512.0f);
    float vs = 0.f;
    #pragma unroll
    for (int j = 0; j < 8; ++j) { float d = e[j] - mu; vs += d * d; }
    #pragma unroll
    for (int off = 1; off < 64; off <<= 1) vs += __shfl_xor(vs, off);
    const float inv = rsqrtf(vs * (1.0f / 512.0f) + EPSV);
    float4 g0 = *(const float4*)(g + lane * 8);
    float4 g1 = *(const float4*)(g + lane * 8 + 4);
    float4 b0 = *(const float4*)(b + lane * 8);
    float4 b1 = *(const float4*)(b + lane * 8 + 4);
    float gg[8] = {g0.x, g0.y, g0.z, g0.w, g1.x, g1.y, g1.z, g1.w};
    float bb[8] = {b0.x, b0.y, b0.z, b0.w, b1.x, b1.y, b1.z, b1.w};
    float x8[8];
    #pragma unroll
    for (int j = 0; j < 8; ++j) x8[j] = fmaxf((e[j] - mu) * inv * gg[j] + bb[j], 0.0f);
    // fallback path needs x in global memory
    if (!merged) {
        bool needX = false;
        for (int l = 1; l < L; ++l) needX |= (lvl_flag(scales, l) == 0);
        if (needX) {
            float* q = Xout + (size_t)r * 512 + lane * 8;
            *(float4*)q = make_float4(x8[0], x8[1], x8[2], x8[3]);
            *(float4*)(q + 4) = make_float4(x8[4], x8[5], x8[6], x8[7]);
        }
    }
    // residual recurrence: pack rs_l for every active level; accumulate qsum.
    float q8[8], r8[8];
    #pragma unroll
    for (int j = 0; j < 8; ++j) { q8[j] = 0.f; r8[j] = x8[j]; }
    for (int l = 0; l < L; ++l) {
        const float sc = scales[l];
        float rs8[8];
        #pragma unroll
        for (int j = 0; j < 8; ++j) rs8[j] = r8[j] * sc;
        const bool active = (l == 0) || (merged && !lvl_flag(scales, l)); // block-uniform
        if (active) {
            float rn = 0.f;
            #pragma unroll
            for (int j = 0; j < 8; ++j) rn += rs8[j] * rs8[j];
            #pragma unroll
            for (int off = 1; off < 64; off <<= 1) rn += __shfl_xor(rn, off);
            float* ndst = (l == 0) ? rsn : (rsnL + (size_t)(l - 1) * M);
            if (lane == 0) ndst[r] = rn;
            short4 pa, pb;
            pa.x = f2bf(rs8[0]); pa.y = f2bf(rs8[1]); pa.z = f2bf(rs8[2]); pa.w = f2bf(rs8[3]);
            pb.x = f2bf(rs8[4]); pb.y = f2bf(rs8[5]); pb.z = f2bf(rs8[6]); pb.w = f2bf(rs8[7]);
            *(short4*)&plds[wv * 520 + lane * 8] = pa;
            *(short4*)&plds[wv * 520 + lane * 8 + 4] = pb;
            __syncthreads();
            short* dst = (l == 0) ? P1 : (P1L + (size_t)(l - 1) * M * 512);
            const int t = threadIdx.x;
            const int kb = t >> 2, rr = t & 3;
            int4 v = *(const int4*)&plds[rr * 520 + kb * 8];
            *(int4*)(dst + ((size_t)kb * M + rb + rr) * 8) = v;
            __syncthreads();
        }
        #pragma unroll
        for (int j = 0; j < 8; ++j) { q8[j] += rs8[j]; r8[j] -= rs8[j] / sc; }
    }
    // LN(qsum), no affine
    float s2 = 0.f;
    #pragma unroll
    for (int j = 0; j < 8; ++j) s2 += q8[j];
    #pragma unroll
    for (int off = 1; off < 64; off <<= 1) s2 += __shfl_xor(s2, off);
    const float mu2 = s2 * (1.0f / 512.0f);
    float v2 = 0.f;
    #pragma unroll
    for (int j = 0; j < 8; ++j) { float d = q8[j] - mu2; v2 += d * d; }
    #pragma unroll
    for (int off = 1; off < 64; off <<= 1) v2 += __shfl_xor(v2, off);
    const float inv2 = rsqrtf(v2 * (1.0f / 512.0f) + EPSV);
    float* q = outln + (size_t)r * 512 + lane * 8;
    *(float4*)q = make_float4((q8[0] - mu2) * inv2, (q8[1] - mu2) * inv2,
                              (q8[2] - mu2) * inv2, (q8[3] - mu2) * inv2);
    *(float4*)(q + 4) = make_float4((q8[4] - mu2) * inv2, (q8[5] - mu2) * inv2,
                                    (q8[6] - mu2) * inv2, (q8[7] - mu2) * inv2);
}

// ---------------- dist_all: level-0 GEMM (first) + merged-level GEMMs + flagged
//                  broadcast (rows 64..127/tile), XCD-swizzled rows ----------------
__global__ __launch_bounds__(256) void dist_all(
    const short* __restrict__ P1, const short* __restrict__ cbp0,
    const float* __restrict__ rsn,
    const short* __restrict__ P1L, const short* __restrict__ cbpL,
    const float* __restrict__ rsnL,
    const float* __restrict__ cn, const float* __restrict__ scales,
    const float* __restrict__ temp_p, float* __restrict__ out,
    int M, int K, int Kd, int LK, int merged) {
    const int G = K >> 7;
    const int lvl = blockIdx.y / G, byg = blockIdx.y % G;
    int bx = blockIdx.x; const int nx = gridDim.x;
    if ((nx & 7) == 0) { const int c = nx >> 3; bx = (bx & 7) * c + (bx >> 3); }
    const int r0 = bx * 128;
    const float inv_t = 1.0f / fmaxf(temp_p[0], TEMP_MINV);
    if (lvl > 0) {
        if (lvl_flag(scales, lvl)) {
            const int cg0 = lvl * K + byg * 128;
            const int tc = (threadIdx.x & 31) << 2, tr = threadIdx.x >> 5;
            float4 cv = *(const float4*)(cn + cg0 + tc);
            float4 v = make_float4(-cv.x * inv_t, -cv.y * inv_t, -cv.z * inv_t, -cv.w * inv_t);
            #pragma unroll
            for (int i = 8; i < 16; ++i) {        // rows 64..127 (gemm1 did 0..63)
                const int r = r0 + i * 8 + tr;
                *(float4*)(out + (size_t)r * LK + cg0 + tc) = v;
            }
            return;
        }
        if (!merged) return;                      // fallback path handles this level
    }
    const short* Ap = (lvl == 0) ? P1 : (P1L + (size_t)(lvl - 1) * M * Kd);
    const short* Bp = (lvl == 0) ? cbp0 : (cbpL + (size_t)(lvl - 1) * K * Kd);
    const float* rs = (lvl == 0) ? rsn : (rsnL + (size_t)(lvl - 1) * M);
    const int cl0 = byg * 128, cg0 = lvl * K + cl0;
    __shared__ __align__(16) short As[8 * 128 * 8];
    __shared__ __align__(16) short Bs[8 * 128 * 8];
    const int lane = threadIdx.x & 63, w = threadIdx.x >> 6;
    const int wm = (w & 1) << 6, wn = (w >> 1) << 6;
    const int fr = lane & 15, fo = lane >> 4;
    f32x4 acc[4][4];
    #pragma unroll
    for (int a = 0; a < 4; ++a)
        #pragma unroll
        for (int b = 0; b < 4; ++b) acc[a][b] = (f32x4){0.f, 0.f, 0.f, 0.f};
    for (int k0 = 0; k0 < Kd; k0 += 64) {
        const int kb0 = k0 >> 3;
        __syncthreads();
        #pragma unroll
        for (int sidx = 0; sidx < 2; ++sidx) {
            const int kblk = (w << 1) + sidx;
            const short* ga = Ap + ((size_t)(kb0 + kblk) * M + r0) * 8;
            const short* gb = Bp + ((size_t)(kb0 + kblk) * K + cl0) * 8;
            short* la = &As[kblk * 128 * 8];
            short* lb = &Bs[kblk * 128 * 8];
            #pragma unroll
            for (int h = 0; h < 2; ++h) {
                gload16(ga + ((h << 6) + lane) * 8, la + (h << 6) * 8);
                gload16(gb + ((h << 6) + lane) * 8, lb + (h << 6) * 8);
            }
        }
        __syncthreads();
        #pragma unroll
        for (int s = 0; s < 2; ++s) {
            const int kb = (s << 2) + fo;
            bf16x8 af[4], bfv[4];
            #pragma unroll
            for (int mt = 0; mt < 4; ++mt)
                af[mt] = *(const bf16x8*)&As[(kb * 128 + wm + mt * 16 + fr) * 8];
            #pragma unroll
            for (int nt = 0; nt < 4; ++nt)
                bfv[nt] = *(const bf16x8*)&Bs[(kb * 128 + wn + nt * 16 + fr) * 8];
            #pragma unroll
            for (int mt = 0; mt < 4; ++mt)
                #pragma unroll
                for (int nt = 0; nt < 4; ++nt)
                    acc[mt][nt] = __builtin_amdgcn_mfma_f32_16x16x32_bf16(af[mt], bfv[nt], acc[mt][nt], 0, 0, 0);
        }
    }
    #pragma unroll
    for (int mt = 0; mt < 4; ++mt) {
        #pragma unroll
        for (int reg = 0; reg < 4; ++reg) {
            const int r = r0 + wm + mt * 16 + (fo << 2) + reg;
            const float rn = rs[r];
            float* orow = out + (size_t)r * LK;
            #pragma unroll
            for (int nt = 0; nt < 4; ++nt) {
                const int c = cg0 + wn + nt * 16 + fr;
                orow[c] = -(rn + cn[c] - 2.0f * acc[mt][nt][reg]) * inv_t;
            }
        }
    }
}

// ---------------- fallback (ws too small): per-level prep + dist ----------------
__global__ __launch_bounds__(256) void prep_level_fb(
    const float* __restrict__ x, const float* __restrict__ cb,
    const float* __restrict__ scales, int l,
    short* __restrict__ cbp, short* __restrict__ P1, float* __restrict__ rsn,
    int M, int K, int D) {
    if (lvl_flag(scales, l)) return;
    __shared__ __align__(16) short lds[32 * 520];
    int gid = blockIdx.x;
    const int nC = K / 32, nX = M / 32;
    if (gid < nC) { pack_block(cb + (size_t)l * K * D, cbp, K, gid * 32, lds); return; }
    gid -= nC;
    if (gid < nX) { pack_block_rec(x, P1, M, gid * 32, lds, scales, l); return; }
    gid -= nX;
    const int wv = threadIdx.x >> 6, lane = threadIdx.x & 63;
    const int row = gid * 4 + wv;
    if (row >= M) return;
    const float* p = x + (size_t)row * 512;
    float s = 0.f;
    for (int j = lane; j < 512; j += 64) {
        float r_ = p[j];
        for (int q = 0; q < l; ++q) { float sc = scales[q]; float rv = r_ * sc; r_ -= rv / sc; }
        r_ *= scales[l];
        s += r_ * r_;
    }
    #pragma unroll
    for (int off = 32; off; off >>= 1) s += __shfl_down(s, off);
    if (lane == 0) rsn[row] = s;
}

__global__ __launch_bounds__(256) void dist_level_fb(
    const short* __restrict__ Ap, const short* __restrict__ Bp,
    const float* __restrict__ rsn, const float* __restrict__ cn,
    const float* __restrict__ temp_p, const float* __restrict__ scales,
    float* __restrict__ out, int M, int K, int Kd, int LK, int lvl) {
    if (lvl_flag(scales, lvl)) return;
    __shared__ __align__(16) short As[8 * 128 * 8];
    __shared__ __align__(16) short Bs[8 * 128 * 8];
    int bx = blockIdx.x; const int nx = gridDim.x;
    if ((nx & 7) == 0) { const int c = nx >> 3; bx = (bx & 7) * c + (bx >> 3); }
    const int r0 = bx * 128;
    const int cl0 = blockIdx.y * 128, cg0 = lvl * K + cl0;
    const float inv_t = 1.0f / fmaxf(temp_p[0], TEMP_MINV);
    const int lane = threadIdx.x & 63, w = threadIdx.x >> 6;
    const int wm = (w & 1) << 6, wn = (w >> 1) << 6;
    const int fr = lane & 15, fo = lane >> 4;
    f32x4 acc[4][4];
    #pragma unroll
    for (int a = 0; a < 4; ++a)
        #pragma unroll
        for (int b = 0; b < 4; ++b) acc[a][b] = (f32x4){0.f, 0.f, 0.f, 0.f};
    for (int k0 = 0; k0 < Kd; k0 += 64) {
        const int kb0 = k0 >> 3;
        __syncthreads();
        #pragma unroll
        for (int sidx = 0; sidx < 2; ++sidx) {
            const int kblk = (w << 1) + sidx;
            const short* ga = Ap + ((size_t)(kb0 + kblk) * M + r0) * 8;
            const short* gb = Bp + ((size_t)(kb0 + kblk) * K + cl0) * 8;
            short* la = &As[kblk * 128 * 8];
            short* lb = &Bs[kblk * 128 * 8];
            #pragma unroll
            for (int h = 0; h < 2; ++h) {
                gload16(ga + ((h << 6) + lane) * 8, la + (h << 6) * 8);
                gload16(gb + ((h << 6) + lane) * 8, lb + (h << 6) * 8);
            }
        }
        __syncthreads();
        #pragma unroll
        for (int s = 0; s < 2; ++s) {
            const int kb = (s << 2) + fo;
            bf16x8 af[4], bfv[4];
            #pragma unroll
            for (int mt = 0; mt < 4; ++mt)
                af[mt] = *(const bf16x8*)&As[(kb * 128 + wm + mt * 16 + fr) * 8];
            #pragma unroll
            for (int nt = 0; nt < 4; ++nt)
                bfv[nt] = *(const bf16x8*)&Bs[(kb * 128 + wn + nt * 16 + fr) * 8];
            #pragma unroll
            for (int mt = 0; mt < 4; ++mt)
                #pragma unroll
                for (int nt = 0; nt < 4; ++nt)
                    acc[mt][nt] = __builtin_amdgcn_mfma_f32_16x16x32_bf16(af[mt], bfv[nt], acc[mt][nt], 0, 0, 0);
        }
    }
    #pragma unroll
    for (int mt = 0; mt < 4; ++mt) {
        #pragma unroll
        for (int reg = 0; reg < 4; ++reg) {
            const int r = r0 + wm + mt * 16 + (fo << 2) + reg;
            const float rn = rsn[r];
            float* orow = out + (size_t)r * LK;
            #pragma unroll
            for (int nt = 0; nt < 4; ++nt) {
                const int c = cg0 + wn + nt * 16 + fr;
                orow[c] = -(rn + cn[c] - 2.0f * acc[mt][nt][reg]) * inv_t;
            }
        }
    }
}

extern "C" void kernel_launch(void* const* d_in, const int* in_sizes, int n_in,
                              void* d_out, int out_size, void* d_ws, size_t ws_size,
                              hipStream_t stream) {
    const float* features = (const float*)d_in[0];
    const float* W        = (const float*)d_in[1];
    const float* bproj    = (const float*)d_in[2];
    const float* lng      = (const float*)d_in[3];
    const float* lnb      = (const float*)d_in[4];
    const float* cb       = (const float*)d_in[5];
    const float* scales   = (const float*)d_in[6];
    const float* temp     = (const float*)d_in[7];

    const int D = in_sizes[2];            // 512
    const int M = in_sizes[0] / D;        // 8192
    const int L = in_sizes[6];            // 4
    const int K = in_sizes[5] / (L * D);  // 2048
    const int LK = L * K;
    const int G = K / 128;

    float* out    = (float*)d_out;                 // [M, L*K]
    float* out_ln = out + (size_t)M * LK;          // [M, D]

    // workspace (floats): x[M*D] | y[M*D] | P1(M*D bf16) | Wp(D*D bf16) | cbp0(K*D bf16)
    //                     | rsn[M] | cn[LK] | pad | [merged: P1L | cbpL | rsnL per extra level]
    float* ws = (float*)d_ws;
    float* x  = ws;
    float* y  = x + (size_t)M * D;
    short* P1 = (short*)(y + (size_t)M * D);
    float* aP1 = y + (size_t)M * D + (size_t)M * D / 2;
    short* Wp = (short*)aP1;
    float* aWp = aP1 + (size_t)D * D / 2;
    short* cbp0 = (short*)aWp;
    float* rsn = aWp + (size_t)K * D / 2;
    float* cn  = rsn + M;
    float* tail = cn + (size_t)LK + 64;

    const size_t baseF = (size_t)(tail - ws);
    const size_t extraF = (size_t)(L - 1) * ((size_t)M * D / 2 + (size_t)K * D / 2 + (size_t)M);
    const int merged = (L <= 1) || (ws_size >= (baseF + extraF) * sizeof(float)) ? 1 : 0;

    short* P1L = (short*)tail;
    short* cbpL = P1L + (size_t)(L - 1) * M * D;
    float* rsnL = (float*)(cbpL + (size_t)(L - 1) * K * D);

    // 1) all input packing + codebook norms (+ gated extra-level cb packs)
    const int nPrep = M / 32 + D / 32 + K / 32 + (LK + 15) / 16 + (L - 1) * (K / 32);
    prep_inputs<<<nPrep, 256, 0, stream>>>(features, W, cb, scales,
                                           P1, Wp, cbp0, cbpL, cn, M, D, K, L, LK, merged);

    // 2) y = features @ W^T + b  |  + flagged-level broadcast (rows 0..63 per tile)
    gemm1_bcast<<<dim3(M / 128, D / 128 + (L - 1) * G), 256, 0, stream>>>(
        P1, Wp, bproj, y, cn, temp, scales, out, M, D, D, K, LK);

    // 3) LN+ReLU ; per-level residual packs + norms ; qsum ; LN(qsum)
    fused_epi<<<M / 4, 256, 0, stream>>>(y, x, P1, rsn, out_ln, lng, lnb, scales,
                                         P1L, rsnL, M, L, merged);

    // 4) all dist GEMMs + flagged broadcast (rows 64..127 per tile)
    dist_all<<<dim3(M / 128, L * G), 256, 0, stream>>>(
        P1, cbp0, rsn, P1L, cbpL, rsnL, cn, scales, temp, out, M, K, D, LK, merged);

    // fallback: sequential per-level path when workspace can't hold per-level buffers
    if (!merged && L > 1) {
        const int nPl = K / 32 + M / 32 + M / 4;
        for (int l = 1; l < L; ++l) {
            prep_level_fb<<<nPl, 256, 0, stream>>>(x, cb, scales, l, cbp0, P1, rsn, M, K, D);
            dist_level_fb<<<dim3(M / 128, G), 256, 0, stream>>>(
                P1, cbp0, rsn, cn, temp, scales, out, M, K, D, LK, l);
        }
    }
}